// Round 3
// baseline (479.385 us; speedup 1.0000x reference)
//
#include <hip/hip_runtime.h>
#include <stdint.h>
#include <stddef.h>

#define BATCH 32768
#define HDIM  1024
#define NFAM  10

typedef short bf16x8 __attribute__((ext_vector_type(8)));
typedef float f32x4  __attribute__((ext_vector_type(4)));

// fp32 -> bf16 round-to-nearest-even
__device__ __forceinline__ unsigned short f2bf(float x) {
  unsigned int u = __builtin_bit_cast(unsigned int, x);
  u += 0x7fffu + ((u >> 16) & 1u);
  return (unsigned short)(u >> 16);
}

// async global->LDS, 16B per lane. LDS dest must be wave-uniform base + lane*16.
__device__ __forceinline__ void async_cp16(unsigned short* lds_dst, const unsigned short* g_src) {
  __builtin_amdgcn_global_load_lds(
      (const __attribute__((address_space(1))) unsigned int*)g_src,
      (__attribute__((address_space(3))) unsigned int*)lds_dst,
      16, 0, 0);
}

// ---------------------------------------------------------------------------
// Transpose + cast: in f32 [R][C] row-major -> out bf16 [C][R]
// ---------------------------------------------------------------------------
__global__ __launch_bounds__(256) void transpose_cast(
    const float* __restrict__ in, unsigned short* __restrict__ out, int R, int C) {
  __shared__ float tile[64][65];
  const int t = threadIdx.x;
  const int c = t & 63;
  const int r0 = t >> 6;
  const int rbase = blockIdx.y * 64, cbase = blockIdx.x * 64;
#pragma unroll
  for (int i = 0; i < 16; ++i) {
    int r = r0 + i * 4;
    tile[r][c] = in[(size_t)(rbase + r) * C + cbase + c];
  }
  __syncthreads();
#pragma unroll
  for (int i = 0; i < 16; ++i) {
    int r = r0 + i * 4;
    out[(size_t)(cbase + r) * R + rbase + c] = f2bf(tile[c][r]);
  }
}

// ---------------------------------------------------------------------------
// Prototype squared norms. One block per family.
// ---------------------------------------------------------------------------
__global__ __launch_bounds__(256) void proto_prep(
    const float* __restrict__ protos, float* __restrict__ p2) {
  __shared__ float red[4];
  const int j = blockIdx.x, t = threadIdx.x;
  float4 v = ((const float4*)(protos + (size_t)j * HDIM))[t];
  float s = v.x * v.x + v.y * v.y + v.z * v.z + v.w * v.w;
#pragma unroll
  for (int o = 32; o > 0; o >>= 1) s += __shfl_down(s, o);
  if ((t & 63) == 0) red[t >> 6] = s;
  __syncthreads();
  if (t == 0) p2[j] = red[0] + red[1] + red[2] + red[3];
}

// ---------------------------------------------------------------------------
// protoC[j][n] = b1[n] + sum_k protos[j][k] * W1[H + k][n]   (fp32)
// Parallel over k: grid (16 n-chunks of 64, NFAM). Block = 4 waves, each wave
// owns a 256-wide k-strip (wave-uniform proto reads -> s_loads), LDS reduce.
// ---------------------------------------------------------------------------
__global__ __launch_bounds__(256) void proto_contrib(
    const float* __restrict__ protos, const float* __restrict__ W1,
    const float* __restrict__ b1, float* __restrict__ protoC) {
  __shared__ float red[4][64];
  const int j  = blockIdx.y;
  const int ln = threadIdx.x & 63;               // n within chunk
  const int ks = threadIdx.x >> 6;               // k-strip 0..3
  const int n  = blockIdx.x * 64 + ln;
  const float* p = protos + (size_t)j * HDIM + ks * 256;
  const float* w = W1 + (size_t)(HDIM + ks * 256) * HDIM + n;
  float s = 0.f;
#pragma unroll 16
  for (int kk = 0; kk < 256; ++kk)
    s += p[kk] * w[(size_t)kk * HDIM];
  red[ks][ln] = s;
  __syncthreads();
  if (ks == 0)
    protoC[j * HDIM + n] = red[0][ln] + red[1][ln] + red[2][ln] + red[3][ln] + b1[n];
}

// ---------------------------------------------------------------------------
// Nearest prototype + features->bf16 cast.
// Protos cached in LDS (40 KB). 16 rows/block: 4 waves x 4 rows sequential.
// ---------------------------------------------------------------------------
__global__ __launch_bounds__(256) void nearest_kernel(
    const float* __restrict__ feats, const float* __restrict__ protos,
    const float* __restrict__ p2, unsigned short* __restrict__ featsB,
    int* __restrict__ idx) {
  __shared__ float pl[NFAM * HDIM];  // fp32 protos, 40 KB
  const int t = threadIdx.x;
#pragma unroll
  for (int j = 0; j < NFAM; ++j)
    ((float4*)pl)[t + 256 * j] = ((const float4*)protos)[t + 256 * j];
  __syncthreads();

  const int wave = t >> 6, lane = t & 63;
  float P2[NFAM];
#pragma unroll
  for (int j = 0; j < NFAM; ++j) P2[j] = p2[j];

#pragma unroll
  for (int rr = 0; rr < 4; ++rr) {
    const int row = blockIdx.x * 16 + wave * 4 + rr;
    const float* f = feats + (size_t)row * HDIM;

    float dot[NFAM];
#pragma unroll
    for (int j = 0; j < NFAM; ++j) dot[j] = 0.f;
    float f2 = 0.f;

#pragma unroll
    for (int ch = 0; ch < 4; ++ch) {
      const int k4 = ch * 64 + lane;  // float4 index within row
      float4 v = ((const float4*)f)[k4];
      f2 += v.x * v.x + v.y * v.y + v.z * v.z + v.w * v.w;
#pragma unroll
      for (int j = 0; j < NFAM; ++j) {
        float4 p = ((const float4*)pl)[j * 256 + k4];
        dot[j] += v.x * p.x + v.y * p.y + v.z * p.z + v.w * p.w;
      }
      uint2 pk;
      pk.x = (unsigned)f2bf(v.x) | ((unsigned)f2bf(v.y) << 16);
      pk.y = (unsigned)f2bf(v.z) | ((unsigned)f2bf(v.w) << 16);
      *(uint2*)(featsB + (size_t)row * HDIM + k4 * 4) = pk;
    }

#pragma unroll
    for (int o = 32; o > 0; o >>= 1) {
      f2 += __shfl_down(f2, o);
#pragma unroll
      for (int j = 0; j < NFAM; ++j) dot[j] += __shfl_down(dot[j], o);
    }
    if (lane == 0) {
      int best = 0;
      float bd = f2 + P2[0] - 2.f * dot[0];
#pragma unroll
      for (int j = 1; j < NFAM; ++j) {
        float d = f2 + P2[j] - 2.f * dot[j];
        if (d < bd) { bd = d; best = j; }
      }
      idx[row] = best;
    }
  }
}

// ---------------------------------------------------------------------------
// 256x256 8-phase bf16 GEMM (K=1024), plain-HIP port of the m201 schedule.
// 512 threads = 8 waves as 2M x 4N; per-wave output 128x64; BK=64.
// LDS 128 KB: per operand [2 buf][2 ksub][2 half][128 rows][32 el], same
// XOR piece-swizzle as proven 128^2 kernel (slot p holds global piece
// p ^ ((row>>1)&3)); staged with pre-swizzled global source (rule 21).
// Per K-tile: 4 phases. Phase ph stages one (op,half) slice-pair of tile t+1
// (2 gload_lds), waits counted vmcnt(6) (ph3: no-op 8), s_barrier, then
// 12 ds_read_b128 + 16 MFMA (one C-quadrant) under setprio(1), s_barrier.
// Stage order [Ah0, Bh0, Ah1, Bh1] + quadrant order (0,0),(1,0),(0,1),(1,1)
// makes vmcnt(6) exactly sufficient at every wait (FIFO enumeration: the 3
// slices left in flight are precisely the not-yet-needed ones). Tile-boundary
// WAR (stage into buf p while it's still read) is excluded by the ph3 end
// barrier. Last tile stages wrapped kb=0 (harmless) to keep waits uniform.
// EPI=1: out = relu(acc + protoC[idx[row]][col]) -> bf16   (protoC holds b1)
// EPI=0: out = acc + bias[col] -> f32
// ---------------------------------------------------------------------------
template <int EPI>
__global__ __launch_bounds__(512, 2) void gemm256(
    const unsigned short* __restrict__ A,   // [M][1024] bf16
    const unsigned short* __restrict__ Bt,  // [1024][1024] bf16, n-major
    const int* __restrict__ idx,            // [M]            (EPI=1)
    const float* __restrict__ protoC,       // [NFAM][1024]   (EPI=1)
    const float* __restrict__ bias,         // [1024]         (EPI=0)
    unsigned short* __restrict__ outB,      // [M][1024] bf16 (EPI=1)
    float* __restrict__ outF) {             // [M][1024] f32  (EPI=0)
  constexpr int K  = 1024;
  constexpr int NT = K / 64;                   // 16 K-tiles
  __shared__ unsigned short ldsA[2 * 2 * 2 * 128 * 32];  // 64 KB
  __shared__ unsigned short ldsB[2 * 2 * 2 * 128 * 32];  // 64 KB

  const int t    = threadIdx.x;
  const int lane = t & 63;
  const int quad = lane >> 4;
  const int r16  = lane & 15;
  const int wid  = t >> 6;
  const int wm   = wid >> 2;                   // 0..1
  const int wn   = wid & 3;                    // 0..3

  // XCD-aware decode: xcd = b&7 owns row-panels [xcd*16, +16), sweeps 4 cols.
  const int b = blockIdx.x;
  const int rowBase = ((b >> 5) + (b & 7) * 16) * 256;
  const int colBase = ((b >> 3) & 3) * 256;

  // staging: thread t covers slice-row sr = t>>2, piece p = t&3 of each
  // 8 KB (ksub,half) slice; swizzled global piece q = p ^ ((sr>>1)&3).
  const int sr = t >> 2;
  const int q  = (t & 3) ^ ((t >> 3) & 3);
  const unsigned short* pA = A  + (size_t)(rowBase + sr) * K + q * 8;
  const unsigned short* pB = Bt + (size_t)(colBase + sr) * K + q * 8;
  const int ldst = t * 8;                      // thread's element offset in a slice

  // reader piece (per-lane constant): global quad lives at LDS piece
  // quad ^ ((r16>>1)&3)   (all row bases are multiples of 8)
  const int pr = quad ^ ((r16 >> 1) & 3);

  f32x4 acc[2][2][4][2];                       // [ah][bh][mi][ni]
#pragma unroll
  for (int a0 = 0; a0 < 2; ++a0)
#pragma unroll
    for (int b0 = 0; b0 < 2; ++b0)
#pragma unroll
      for (int m0 = 0; m0 < 4; ++m0)
#pragma unroll
        for (int n0 = 0; n0 < 2; ++n0) acc[a0][b0][m0][n0] = (f32x4){0.f, 0.f, 0.f, 0.f};

  // stage one (op, half) slice-pair (ksub 0 and 1) of a tile: 2 loads/thread.
#define STAGE_A(buf, h, kb)                                                        \
  {                                                                                \
    async_cp16(ldsA + (buf) * 16384 + (0 * 2 + (h)) * 4096 + ldst,                 \
               pA + (size_t)(h) * (128 * K) + (kb) + 0 * 32);                      \
    async_cp16(ldsA + (buf) * 16384 + (1 * 2 + (h)) * 4096 + ldst,                 \
               pA + (size_t)(h) * (128 * K) + (kb) + 1 * 32);                      \
  }
#define STAGE_B(buf, h, kb)                                                        \
  {                                                                                \
    async_cp16(ldsB + (buf) * 16384 + (0 * 2 + (h)) * 4096 + ldst,                 \
               pB + (size_t)(h) * (128 * K) + (kb) + 0 * 32);                      \
    async_cp16(ldsB + (buf) * 16384 + (1 * 2 + (h)) * 4096 + ldst,                 \
               pB + (size_t)(h) * (128 * K) + (kb) + 1 * 32);                      \
  }

  // prologue: stage tile 0 into buf 0, in the canonical order.
  STAGE_A(0, 0, 0);
  STAGE_B(0, 0, 0);
  STAGE_A(0, 1, 0);
  STAGE_B(0, 1, 0);

  for (int kt = 0; kt < NT; ++kt) {
    const int p   = kt & 1;
    const int kbn = ((kt + 1) & (NT - 1)) * 64;   // wrapped next-tile kb
#pragma unroll
    for (int ph = 0; ph < 4; ++ph) {
      // stage one slice-pair of tile t+1 into buf p^1
      if (ph == 0)      STAGE_A(p ^ 1, 0, kbn)
      else if (ph == 1) STAGE_B(p ^ 1, 0, kbn)
      else if (ph == 2) STAGE_A(p ^ 1, 1, kbn)
      else              STAGE_B(p ^ 1, 1, kbn)

      if (ph == 3) asm volatile("s_waitcnt vmcnt(8)" ::: "memory");
      else         asm volatile("s_waitcnt vmcnt(6)" ::: "memory");
      asm volatile("s_barrier" ::: "memory");
      __builtin_amdgcn_sched_barrier(0);

      const int ah = ph & 1;        // quadrant order (0,0),(1,0),(0,1),(1,1)
      const int bh = ph >> 1;

      bf16x8 av[2][4], bv[2][2];
#pragma unroll
      for (int s = 0; s < 2; ++s)
#pragma unroll
        for (int mi = 0; mi < 4; ++mi)
          av[s][mi] = *(const bf16x8*)(ldsA + p * 16384 + (s * 2 + ah) * 4096 +
                                       (wm * 64 + mi * 16 + r16) * 32 + pr * 8);
#pragma unroll
      for (int s = 0; s < 2; ++s)
#pragma unroll
        for (int ni = 0; ni < 2; ++ni)
          bv[s][ni] = *(const bf16x8*)(ldsB + p * 16384 + (s * 2 + bh) * 4096 +
                                       (wn * 32 + ni * 16 + r16) * 32 + pr * 8);

      __builtin_amdgcn_s_setprio(1);
#pragma unroll
      for (int s = 0; s < 2; ++s)
#pragma unroll
        for (int mi = 0; mi < 4; ++mi)
#pragma unroll
          for (int ni = 0; ni < 2; ++ni)
            acc[ah][bh][mi][ni] = __builtin_amdgcn_mfma_f32_16x16x32_bf16(
                av[s][mi], bv[s][ni], acc[ah][bh][mi][ni], 0, 0, 0);
      __builtin_amdgcn_s_setprio(0);
      __builtin_amdgcn_sched_barrier(0);
      asm volatile("s_barrier" ::: "memory");
    }
  }
#undef STAGE_A
#undef STAGE_B

  // epilogue: C/D layout col=lane&15, row=quad*4+reg  [m89/m91]
#pragma unroll
  for (int ah = 0; ah < 2; ++ah) {
#pragma unroll
    for (int mi = 0; mi < 4; ++mi) {
      const int grow0 = rowBase + ah * 128 + wm * 64 + mi * 16 + quad * 4;
      int pid[4];
      if (EPI) {
#pragma unroll
        for (int r = 0; r < 4; ++r) pid[r] = idx[grow0 + r];  // L2-hot
      }
#pragma unroll
      for (int bh = 0; bh < 2; ++bh) {
#pragma unroll
        for (int ni = 0; ni < 2; ++ni) {
          const int gcol = colBase + bh * 128 + wn * 32 + ni * 16 + r16;
          if (EPI) {
#pragma unroll
            for (int r = 0; r < 4; ++r) {
              float v = acc[ah][bh][mi][ni][r] + protoC[(size_t)pid[r] * HDIM + gcol];
              v = fmaxf(v, 0.0f);
              outB[(size_t)(grow0 + r) * 1024 + gcol] = f2bf(v);
            }
          } else {
            const float bv = bias[gcol];
#pragma unroll
            for (int r = 0; r < 4; ++r)
              outF[(size_t)(grow0 + r) * 1024 + gcol] = acc[ah][bh][mi][ni][r] + bv;
          }
        }
      }
    }
  }
}

// ---------------------------------------------------------------------------
// Workspace layout (~138.4 MB): featsB | hiddenB | W1t | W2t | protoC | p2 | idx
// ---------------------------------------------------------------------------
extern "C" void kernel_launch(void* const* d_in, const int* in_sizes, int n_in,
                              void* d_out, int out_size, void* d_ws, size_t ws_size,
                              hipStream_t stream) {
  const float* feats  = (const float*)d_in[0];
  const float* protos = (const float*)d_in[1];
  const float* W1     = (const float*)d_in[2];
  const float* b1     = (const float*)d_in[3];
  const float* W2     = (const float*)d_in[4];
  const float* b2     = (const float*)d_in[5];
  float* out = (float*)d_out;

  unsigned short* featsB  = (unsigned short*)d_ws;
  unsigned short* hiddenB = featsB + (size_t)BATCH * HDIM;
  unsigned short* W1t     = hiddenB + (size_t)BATCH * HDIM;   // top half only
  unsigned short* W2t     = W1t + (size_t)HDIM * HDIM;
  float* protoC = (float*)(W2t + (size_t)HDIM * HDIM);        // [NFAM][HDIM]
  float* p2     = protoC + NFAM * HDIM;
  int* idx      = (int*)(p2 + NFAM + 2);

  // W1 top half [1024][1024] -> bf16 [n][k]; W2 [1024][1024] -> bf16 [n][k]
  transpose_cast<<<dim3(HDIM / 64, HDIM / 64), 256, 0, stream>>>(W1, W1t, HDIM, HDIM);
  transpose_cast<<<dim3(HDIM / 64, HDIM / 64), 256, 0, stream>>>(W2, W2t, HDIM, HDIM);
  proto_prep<<<NFAM, 256, 0, stream>>>(protos, p2);
  proto_contrib<<<dim3(HDIM / 64, NFAM), 256, 0, stream>>>(protos, W1, b1, protoC);
  nearest_kernel<<<BATCH / 16, 256, 0, stream>>>(feats, protos, p2, featsB, idx);
  // GEMM1: hidden = relu(feats @ W1top + protoC[idx])     K=1024
  gemm256<1><<<512, 512, 0, stream>>>(featsB, W1t, idx, protoC, nullptr, hiddenB, nullptr);
  // GEMM2: out = hidden @ W2 + b2                          K=1024
  gemm256<0><<<512, 512, 0, stream>>>(hiddenB, W2t, nullptr, nullptr, b2, nullptr, out);
}

// Round 4
// 413.235 us; speedup vs baseline: 1.1601x; 1.1601x over previous
//
#include <hip/hip_runtime.h>
#include <stdint.h>
#include <stddef.h>

#define BATCH 32768
#define HDIM  1024
#define NFAM  10

typedef short bf16x8 __attribute__((ext_vector_type(8)));
typedef float f32x4  __attribute__((ext_vector_type(4)));

// fp32 -> bf16 round-to-nearest-even
__device__ __forceinline__ unsigned short f2bf(float x) {
  unsigned int u = __builtin_bit_cast(unsigned int, x);
  u += 0x7fffu + ((u >> 16) & 1u);
  return (unsigned short)(u >> 16);
}

// async global->LDS, 16B per lane. LDS dest must be wave-uniform base + lane*16.
__device__ __forceinline__ void async_cp16(unsigned short* lds_dst, const unsigned short* g_src) {
  __builtin_amdgcn_global_load_lds(
      (const __attribute__((address_space(1))) unsigned int*)g_src,
      (__attribute__((address_space(3))) unsigned int*)lds_dst,
      16, 0, 0);
}

// ---------------------------------------------------------------------------
// Transpose + cast: in f32 [R][C] row-major -> out bf16 [C][R]
// ---------------------------------------------------------------------------
__global__ __launch_bounds__(256) void transpose_cast(
    const float* __restrict__ in, unsigned short* __restrict__ out, int R, int C) {
  __shared__ float tile[64][65];
  const int t = threadIdx.x;
  const int c = t & 63;
  const int r0 = t >> 6;
  const int rbase = blockIdx.y * 64, cbase = blockIdx.x * 64;
#pragma unroll
  for (int i = 0; i < 16; ++i) {
    int r = r0 + i * 4;
    tile[r][c] = in[(size_t)(rbase + r) * C + cbase + c];
  }
  __syncthreads();
#pragma unroll
  for (int i = 0; i < 16; ++i) {
    int r = r0 + i * 4;
    out[(size_t)(cbase + r) * R + rbase + c] = f2bf(tile[c][r]);
  }
}

// ---------------------------------------------------------------------------
// Prototype squared norms. One block per family.
// ---------------------------------------------------------------------------
__global__ __launch_bounds__(256) void proto_prep(
    const float* __restrict__ protos, float* __restrict__ p2) {
  __shared__ float red[4];
  const int j = blockIdx.x, t = threadIdx.x;
  float4 v = ((const float4*)(protos + (size_t)j * HDIM))[t];
  float s = v.x * v.x + v.y * v.y + v.z * v.z + v.w * v.w;
#pragma unroll
  for (int o = 32; o > 0; o >>= 1) s += __shfl_down(s, o);
  if ((t & 63) == 0) red[t >> 6] = s;
  __syncthreads();
  if (t == 0) p2[j] = red[0] + red[1] + red[2] + red[3];
}

// ---------------------------------------------------------------------------
// protoC[j][n] = b1[n] + sum_k protos[j][k] * W1[H + k][n]   (fp32)
// Parallel over k: grid (16 n-chunks of 64, NFAM). Block = 4 waves, each wave
// owns a 256-wide k-strip (wave-uniform proto reads -> s_loads), LDS reduce.
// ---------------------------------------------------------------------------
__global__ __launch_bounds__(256) void proto_contrib(
    const float* __restrict__ protos, const float* __restrict__ W1,
    const float* __restrict__ b1, float* __restrict__ protoC) {
  __shared__ float red[4][64];
  const int j  = blockIdx.y;
  const int ln = threadIdx.x & 63;               // n within chunk
  const int ks = threadIdx.x >> 6;               // k-strip 0..3
  const int n  = blockIdx.x * 64 + ln;
  const float* p = protos + (size_t)j * HDIM + ks * 256;
  const float* w = W1 + (size_t)(HDIM + ks * 256) * HDIM + n;
  float s = 0.f;
#pragma unroll 16
  for (int kk = 0; kk < 256; ++kk)
    s += p[kk] * w[(size_t)kk * HDIM];
  red[ks][ln] = s;
  __syncthreads();
  if (ks == 0)
    protoC[j * HDIM + n] = red[0][ln] + red[1][ln] + red[2][ln] + red[3][ln] + b1[n];
}

// ---------------------------------------------------------------------------
// Nearest prototype + features->bf16 cast.
// Protos cached in LDS (40 KB). 16 rows/block: 4 waves x 4 rows sequential.
// ---------------------------------------------------------------------------
__global__ __launch_bounds__(256) void nearest_kernel(
    const float* __restrict__ feats, const float* __restrict__ protos,
    const float* __restrict__ p2, unsigned short* __restrict__ featsB,
    int* __restrict__ idx) {
  __shared__ float pl[NFAM * HDIM];  // fp32 protos, 40 KB
  const int t = threadIdx.x;
#pragma unroll
  for (int j = 0; j < NFAM; ++j)
    ((float4*)pl)[t + 256 * j] = ((const float4*)protos)[t + 256 * j];
  __syncthreads();

  const int wave = t >> 6, lane = t & 63;
  float P2[NFAM];
#pragma unroll
  for (int j = 0; j < NFAM; ++j) P2[j] = p2[j];

#pragma unroll
  for (int rr = 0; rr < 4; ++rr) {
    const int row = blockIdx.x * 16 + wave * 4 + rr;
    const float* f = feats + (size_t)row * HDIM;

    float dot[NFAM];
#pragma unroll
    for (int j = 0; j < NFAM; ++j) dot[j] = 0.f;
    float f2 = 0.f;

#pragma unroll
    for (int ch = 0; ch < 4; ++ch) {
      const int k4 = ch * 64 + lane;  // float4 index within row
      float4 v = ((const float4*)f)[k4];
      f2 += v.x * v.x + v.y * v.y + v.z * v.z + v.w * v.w;
#pragma unroll
      for (int j = 0; j < NFAM; ++j) {
        float4 p = ((const float4*)pl)[j * 256 + k4];
        dot[j] += v.x * p.x + v.y * p.y + v.z * p.z + v.w * p.w;
      }
      uint2 pk;
      pk.x = (unsigned)f2bf(v.x) | ((unsigned)f2bf(v.y) << 16);
      pk.y = (unsigned)f2bf(v.z) | ((unsigned)f2bf(v.w) << 16);
      *(uint2*)(featsB + (size_t)row * HDIM + k4 * 4) = pk;
    }

#pragma unroll
    for (int o = 32; o > 0; o >>= 1) {
      f2 += __shfl_down(f2, o);
#pragma unroll
      for (int j = 0; j < NFAM; ++j) dot[j] += __shfl_down(dot[j], o);
    }
    if (lane == 0) {
      int best = 0;
      float bd = f2 + P2[0] - 2.f * dot[0];
#pragma unroll
      for (int j = 1; j < NFAM; ++j) {
        float d = f2 + P2[j] - 2.f * dot[j];
        if (d < bd) { bd = d; best = j; }
      }
      idx[row] = best;
    }
  }
}

// ---------------------------------------------------------------------------
// 256x256 8-phase bf16 GEMM (K=1024), schedule v2 (m201-faithful).
// 512 threads = 8 waves as 2M x 4N; per-wave output 128x64; BK=64.
// LDS 128 KB: per operand [2 buf][2 ksub][2 half][128 rows][32 el], XOR
// piece-swizzle (slot p holds global piece p ^ ((row>>1)&3)) staged via
// pre-swizzled global source (rule 21). Refcheck-proven layout from R3.
//
// Per K-tile kt (buf p = kt&1), quadrants (a0,b0),(a0,b1),(a1,b1),(a1,b0):
//   ph0: dsr av<-A-lo(8), bvlo<-B-lo(4); stage T+1:A-hi->p^1; bar; MFMA q00; bar
//   ph1: dsr bvhi<-B-hi(4);              stage T+1:B-lo->p^1; bar; MFMA q01; bar
//   ph2: dsr av<-A-hi(8);                stage T+2:A-lo->p;   bar; MFMA q11; bar
//   ph3: (regs held)                     stage T+2:B-hi->p;   vmcnt(4); bar; MFMA q10; bar
// Register reuse (av 2 phases, bvlo ph0->ph3, bvhi ph1->ph2) makes each
// slice's LAST LDS read early enough that T+2 restage into the CURRENT buf
// is separated from it by >=2 barriers (WAR race-free by barrier ordering).
// One vmcnt(4) per tile: only the 2 slices staged at ph2/ph3 may remain
// outstanding -> all of T+1 has landed (RAW). ds_reads issued BEFORE the
// barrier hide their latency; compiler inserts the RAW lgkmcnt waits.
// Tail tiles stage wrapped kb (harmless; keeps counts uniform).
// EPI=1: out = relu(acc + protoC[idx[row]][col]) -> bf16   (protoC holds b1)
// EPI=0: out = acc + bias[col] -> f32
// ---------------------------------------------------------------------------
template <int EPI>
__global__ __launch_bounds__(512, 2) void gemm256(
    const unsigned short* __restrict__ A,   // [M][1024] bf16
    const unsigned short* __restrict__ Bt,  // [1024][1024] bf16, n-major
    const int* __restrict__ idx,            // [M]            (EPI=1)
    const float* __restrict__ protoC,       // [NFAM][1024]   (EPI=1)
    const float* __restrict__ bias,         // [1024]         (EPI=0)
    unsigned short* __restrict__ outB,      // [M][1024] bf16 (EPI=1)
    float* __restrict__ outF) {             // [M][1024] f32  (EPI=0)
  constexpr int K  = 1024;
  constexpr int NT = K / 64;                   // 16 K-tiles
  __shared__ unsigned short ldsA[2 * 2 * 2 * 128 * 32];  // 64 KB
  __shared__ unsigned short ldsB[2 * 2 * 2 * 128 * 32];  // 64 KB

  const int t    = threadIdx.x;
  const int lane = t & 63;
  const int quad = lane >> 4;
  const int r16  = lane & 15;
  const int wid  = t >> 6;
  const int wm   = wid >> 2;                   // 0..1
  const int wn   = wid & 3;                    // 0..3

  // XCD-aware decode: xcd = b&7 owns row-panels [xcd*16, +16), sweeps 4 cols.
  const int b = blockIdx.x;
  const int rowBase = ((b >> 5) + (b & 7) * 16) * 256;
  const int colBase = ((b >> 3) & 3) * 256;

  // staging: thread t covers slice-row sr = t>>2, piece p = t&3 of each
  // 8 KB (ksub,half) slice; swizzled global piece q = p ^ ((sr>>1)&3).
  const int sr = t >> 2;
  const int q  = (t & 3) ^ ((t >> 3) & 3);
  const unsigned short* pA = A  + (size_t)(rowBase + sr) * K + q * 8;
  const unsigned short* pB = Bt + (size_t)(colBase + sr) * K + q * 8;
  const int ldst = t * 8;                      // thread's element offset in a slice

  // reader piece (per-lane constant)
  const int pr = quad ^ ((r16 >> 1) & 3);

  f32x4 acc[2][2][4][2];                       // [ah][bh][mi][ni]
#pragma unroll
  for (int a0 = 0; a0 < 2; ++a0)
#pragma unroll
    for (int b0 = 0; b0 < 2; ++b0)
#pragma unroll
      for (int m0 = 0; m0 < 4; ++m0)
#pragma unroll
        for (int n0 = 0; n0 < 2; ++n0) acc[a0][b0][m0][n0] = (f32x4){0.f, 0.f, 0.f, 0.f};

#define STAGE_A(buf, h, kb)                                                        \
  {                                                                                \
    async_cp16(ldsA + (buf) * 16384 + (0 * 2 + (h)) * 4096 + ldst,                 \
               pA + (size_t)(h) * (128 * K) + (kb) + 0 * 32);                      \
    async_cp16(ldsA + (buf) * 16384 + (1 * 2 + (h)) * 4096 + ldst,                 \
               pA + (size_t)(h) * (128 * K) + (kb) + 1 * 32);                      \
  }
#define STAGE_B(buf, h, kb)                                                        \
  {                                                                                \
    async_cp16(ldsB + (buf) * 16384 + (0 * 2 + (h)) * 4096 + ldst,                 \
               pB + (size_t)(h) * (128 * K) + (kb) + 0 * 32);                      \
    async_cp16(ldsB + (buf) * 16384 + (1 * 2 + (h)) * 4096 + ldst,                 \
               pB + (size_t)(h) * (128 * K) + (kb) + 1 * 32);                      \
  }
  // ds_read helpers (addresses identical to refcheck-proven R3 reads)
#define READ_A(dst, p_, h)                                                          \
  _Pragma("unroll")                                                                 \
  for (int s = 0; s < 2; ++s)                                                       \
    _Pragma("unroll")                                                               \
    for (int mi = 0; mi < 4; ++mi)                                                  \
      dst[s][mi] = *(const bf16x8*)(ldsA + (p_) * 16384 + (s * 2 + (h)) * 4096 +    \
                                    (wm * 64 + mi * 16 + r16) * 32 + pr * 8);
#define READ_B(dst, p_, h)                                                          \
  _Pragma("unroll")                                                                 \
  for (int s = 0; s < 2; ++s)                                                       \
    _Pragma("unroll")                                                               \
    for (int ni = 0; ni < 2; ++ni)                                                  \
      dst[s][ni] = *(const bf16x8*)(ldsB + (p_) * 16384 + (s * 2 + (h)) * 4096 +    \
                                    (wn * 32 + ni * 16 + r16) * 32 + pr * 8);
#define MFMA_Q(ah, bh, bsrc)                                                        \
  __builtin_amdgcn_s_setprio(1);                                                    \
  _Pragma("unroll")                                                                 \
  for (int s = 0; s < 2; ++s)                                                       \
    _Pragma("unroll")                                                               \
    for (int mi = 0; mi < 4; ++mi)                                                  \
      _Pragma("unroll")                                                             \
      for (int ni = 0; ni < 2; ++ni)                                                \
        acc[ah][bh][mi][ni] = __builtin_amdgcn_mfma_f32_16x16x32_bf16(              \
            av[s][mi], bsrc[s][ni], acc[ah][bh][mi][ni], 0, 0, 0);                  \
  __builtin_amdgcn_s_setprio(0);

  // prologue: issue order matches steady state (per tile: A-lo, B-hi, A-hi, B-lo)
  STAGE_A(0, 0, 0);        // T0 A-lo
  STAGE_B(0, 1, 0);        // T0 B-hi
  STAGE_A(0, 1, 0);        // T0 A-hi
  STAGE_B(0, 0, 0);        // T0 B-lo
  STAGE_A(1, 0, 64);       // T1 A-lo
  STAGE_B(1, 1, 64);       // T1 B-hi
  asm volatile("s_waitcnt vmcnt(4)" ::: "memory");   // T0 fully landed
  __builtin_amdgcn_s_barrier();

  bf16x8 av[2][4], bvlo[2][2], bvhi[2][2];

  for (int kt = 0; kt < NT; ++kt) {
    const int p   = kt & 1;
    const int kb1 = ((kt + 1) & (NT - 1)) * 64;
    const int kb2 = ((kt + 2) & (NT - 1)) * 64;

    // ph0: q(a0,b0)
    READ_A(av, p, 0);
    READ_B(bvlo, p, 0);
    STAGE_A(p ^ 1, 1, kb1);                 // T+1 A-hi
    __builtin_amdgcn_s_barrier();
    MFMA_Q(0, 0, bvlo);
    __builtin_amdgcn_s_barrier();

    // ph1: q(a0,b1)
    READ_B(bvhi, p, 1);
    STAGE_B(p ^ 1, 0, kb1);                 // T+1 B-lo
    __builtin_amdgcn_s_barrier();
    MFMA_Q(0, 1, bvhi);
    __builtin_amdgcn_s_barrier();

    // ph2: q(a1,b1)
    READ_A(av, p, 1);
    STAGE_A(p, 0, kb2);                     // T+2 A-lo (same buf; A-lo last read ph0)
    __builtin_amdgcn_s_barrier();
    MFMA_Q(1, 1, bvhi);
    __builtin_amdgcn_s_barrier();

    // ph3: q(a1,b0)  (all operands already in registers)
    STAGE_B(p, 1, kb2);                     // T+2 B-hi (same buf; B-hi last read ph1)
    asm volatile("s_waitcnt vmcnt(4)" ::: "memory");  // all of T+1 landed
    __builtin_amdgcn_s_barrier();
    MFMA_Q(1, 0, bvlo);
    __builtin_amdgcn_s_barrier();
  }
#undef STAGE_A
#undef STAGE_B
#undef READ_A
#undef READ_B
#undef MFMA_Q

  // epilogue: C/D layout col=lane&15, row=quad*4+reg  [m89/m91]
#pragma unroll
  for (int ah = 0; ah < 2; ++ah) {
#pragma unroll
    for (int mi = 0; mi < 4; ++mi) {
      const int grow0 = rowBase + ah * 128 + wm * 64 + mi * 16 + quad * 4;
      int pid[4];
      if (EPI) {
#pragma unroll
        for (int r = 0; r < 4; ++r) pid[r] = idx[grow0 + r];  // L2-hot
      }
#pragma unroll
      for (int bh = 0; bh < 2; ++bh) {
#pragma unroll
        for (int ni = 0; ni < 2; ++ni) {
          const int gcol = colBase + bh * 128 + wn * 32 + ni * 16 + r16;
          if (EPI) {
#pragma unroll
            for (int r = 0; r < 4; ++r) {
              float v = acc[ah][bh][mi][ni][r] + protoC[(size_t)pid[r] * HDIM + gcol];
              v = fmaxf(v, 0.0f);
              outB[(size_t)(grow0 + r) * 1024 + gcol] = f2bf(v);
            }
          } else {
            const float bv = bias[gcol];
#pragma unroll
            for (int r = 0; r < 4; ++r)
              outF[(size_t)(grow0 + r) * 1024 + gcol] = acc[ah][bh][mi][ni][r] + bv;
          }
        }
      }
    }
  }
}

// ---------------------------------------------------------------------------
// Workspace layout (~138.4 MB): featsB | hiddenB | W1t | W2t | protoC | p2 | idx
// ---------------------------------------------------------------------------
extern "C" void kernel_launch(void* const* d_in, const int* in_sizes, int n_in,
                              void* d_out, int out_size, void* d_ws, size_t ws_size,
                              hipStream_t stream) {
  const float* feats  = (const float*)d_in[0];
  const float* protos = (const float*)d_in[1];
  const float* W1     = (const float*)d_in[2];
  const float* b1     = (const float*)d_in[3];
  const float* W2     = (const float*)d_in[4];
  const float* b2     = (const float*)d_in[5];
  float* out = (float*)d_out;

  unsigned short* featsB  = (unsigned short*)d_ws;
  unsigned short* hiddenB = featsB + (size_t)BATCH * HDIM;
  unsigned short* W1t     = hiddenB + (size_t)BATCH * HDIM;   // top half only
  unsigned short* W2t     = W1t + (size_t)HDIM * HDIM;
  float* protoC = (float*)(W2t + (size_t)HDIM * HDIM);        // [NFAM][HDIM]
  float* p2     = protoC + NFAM * HDIM;
  int* idx      = (int*)(p2 + NFAM + 2);

  // W1 top half [1024][1024] -> bf16 [n][k]; W2 [1024][1024] -> bf16 [n][k]
  transpose_cast<<<dim3(HDIM / 64, HDIM / 64), 256, 0, stream>>>(W1, W1t, HDIM, HDIM);
  transpose_cast<<<dim3(HDIM / 64, HDIM / 64), 256, 0, stream>>>(W2, W2t, HDIM, HDIM);
  proto_prep<<<NFAM, 256, 0, stream>>>(protos, p2);
  proto_contrib<<<dim3(HDIM / 64, NFAM), 256, 0, stream>>>(protos, W1, b1, protoC);
  nearest_kernel<<<BATCH / 16, 256, 0, stream>>>(feats, protos, p2, featsB, idx);
  // GEMM1: hidden = relu(feats @ W1top + protoC[idx])     K=1024
  gemm256<1><<<512, 512, 0, stream>>>(featsB, W1t, idx, protoC, nullptr, hiddenB, nullptr);
  // GEMM2: out = hidden @ W2 + b2                          K=1024
  gemm256<0><<<512, 512, 0, stream>>>(hiddenB, W2t, nullptr, nullptr, b2, nullptr, out);
}

// Round 5
// 398.273 us; speedup vs baseline: 1.2037x; 1.0376x over previous
//
#include <hip/hip_runtime.h>
#include <stdint.h>
#include <stddef.h>

#define BATCH 32768
#define HDIM  1024
#define NFAM  10

typedef short bf16x8 __attribute__((ext_vector_type(8)));
typedef float f32x4  __attribute__((ext_vector_type(4)));

// fp32 -> bf16 round-to-nearest-even
__device__ __forceinline__ unsigned short f2bf(float x) {
  unsigned int u = __builtin_bit_cast(unsigned int, x);
  u += 0x7fffu + ((u >> 16) & 1u);
  return (unsigned short)(u >> 16);
}

// async global->LDS, 16B per lane. LDS dest must be wave-uniform base + lane*16.
__device__ __forceinline__ void async_cp16(unsigned short* lds_dst, const unsigned short* g_src) {
  __builtin_amdgcn_global_load_lds(
      (const __attribute__((address_space(1))) unsigned int*)g_src,
      (__attribute__((address_space(3))) unsigned int*)lds_dst,
      16, 0, 0);
}

// ---------------------------------------------------------------------------
// Fused prep kernel — block-range dispatch, all jobs mutually independent
// (no cross-block dependencies -> dispatch-order-safe, G16).
//   [0, 2048)    nearest-prototype + feats->bf16 cast (p2 computed in-block)
//   [2048, 2304) transpose+cast W1 top half -> W1t  [n][k] bf16
//   [2304, 2560) transpose+cast W2          -> W2t  [n][k] bf16
//   [2560, 2720) protoC[j][n] = b1[n] + protos[j] . W1bottom[:, n]
// Shared LDS union: 40960 B exactly -> 4 blocks/CU for the nearest majority.
// ---------------------------------------------------------------------------
#define NEAREST_BLKS  2048
#define TR1_BASE      2048
#define TR2_BASE      2304
#define CONTRIB_BASE  2560
#define PREP_BLKS     2720

__global__ __launch_bounds__(256) void prep_kernel(
    const float* __restrict__ feats, const float* __restrict__ protos,
    const float* __restrict__ W1, const float* __restrict__ b1,
    const float* __restrict__ W2,
    unsigned short* __restrict__ featsB, int* __restrict__ idx,
    float* __restrict__ protoC,
    unsigned short* __restrict__ W1t, unsigned short* __restrict__ W2t) {
  __shared__ __align__(16) char smem[40960];
  const int b = blockIdx.x;
  const int t = threadIdx.x;

  if (b < NEAREST_BLKS) {
    // ---- nearest + cast ----
    float* pl = (float*)smem;  // fp32 protos, 10*1024 floats = 40960 B
#pragma unroll
    for (int j = 0; j < NFAM; ++j)
      ((float4*)pl)[t + 256 * j] = ((const float4*)protos)[t + 256 * j];
    __syncthreads();

    const int wave = t >> 6, lane = t & 63;

    // per-wave p2 from LDS (lane 0 ends with the full sum; only lane 0 uses it)
    float P2[NFAM];
#pragma unroll
    for (int j = 0; j < NFAM; ++j) {
      float s = 0.f;
#pragma unroll
      for (int c = 0; c < 4; ++c) {
        float4 v = ((const float4*)pl)[j * 256 + c * 64 + lane];
        s += v.x * v.x + v.y * v.y + v.z * v.z + v.w * v.w;
      }
#pragma unroll
      for (int o = 32; o > 0; o >>= 1) s += __shfl_down(s, o);
      P2[j] = s;
    }

#pragma unroll
    for (int rr = 0; rr < 4; ++rr) {
      const int row = b * 16 + wave * 4 + rr;
      const float* f = feats + (size_t)row * HDIM;

      float dot[NFAM];
#pragma unroll
      for (int j = 0; j < NFAM; ++j) dot[j] = 0.f;
      float f2 = 0.f;

#pragma unroll
      for (int ch = 0; ch < 4; ++ch) {
        const int k4 = ch * 64 + lane;  // float4 index within row
        float4 v = ((const float4*)f)[k4];
        f2 += v.x * v.x + v.y * v.y + v.z * v.z + v.w * v.w;
#pragma unroll
        for (int j = 0; j < NFAM; ++j) {
          float4 p = ((const float4*)pl)[j * 256 + k4];
          dot[j] += v.x * p.x + v.y * p.y + v.z * p.z + v.w * p.w;
        }
        uint2 pk;
        pk.x = (unsigned)f2bf(v.x) | ((unsigned)f2bf(v.y) << 16);
        pk.y = (unsigned)f2bf(v.z) | ((unsigned)f2bf(v.w) << 16);
        *(uint2*)(featsB + (size_t)row * HDIM + k4 * 4) = pk;
      }

#pragma unroll
      for (int o = 32; o > 0; o >>= 1) {
        f2 += __shfl_down(f2, o);
#pragma unroll
        for (int j = 0; j < NFAM; ++j) dot[j] += __shfl_down(dot[j], o);
      }
      if (lane == 0) {
        int best = 0;
        float bd = f2 + P2[0] - 2.f * dot[0];
#pragma unroll
        for (int j = 1; j < NFAM; ++j) {
          float d = f2 + P2[j] - 2.f * dot[j];
          if (d < bd) { bd = d; best = j; }
        }
        idx[row] = best;
      }
    }
  } else if (b < CONTRIB_BASE) {
    // ---- transpose + cast: in f32 [1024][1024] -> out bf16 [1024][1024]^T ----
    const int bi = (b < TR2_BASE) ? (b - TR1_BASE) : (b - TR2_BASE);
    const float* in = (b < TR2_BASE) ? W1 : W2;
    unsigned short* out = (b < TR2_BASE) ? W1t : W2t;
    float (*tile)[65] = (float(*)[65])smem;  // 16640 B
    const int c = t & 63;
    const int r0 = t >> 6;
    const int rbase = (bi >> 4) * 64, cbase = (bi & 15) * 64;
#pragma unroll
    for (int i = 0; i < 16; ++i) {
      int r = r0 + i * 4;
      tile[r][c] = in[(size_t)(rbase + r) * HDIM + cbase + c];
    }
    __syncthreads();
#pragma unroll
    for (int i = 0; i < 16; ++i) {
      int r = r0 + i * 4;
      out[(size_t)(cbase + r) * HDIM + rbase + c] = f2bf(tile[c][r]);
    }
  } else {
    // ---- protoC[j][n] = b1[n] + sum_k protos[j][k] * W1[H + k][n] ----
    float (*red)[64] = (float(*)[64])smem;   // 1024 B
    const int bi = b - CONTRIB_BASE;         // 0..159
    const int j  = bi >> 4;
    const int nc = bi & 15;
    const int ln = t & 63;
    const int ks = t >> 6;
    const int n  = nc * 64 + ln;
    const float* p = protos + (size_t)j * HDIM + ks * 256;
    const float* w = W1 + (size_t)(HDIM + ks * 256) * HDIM + n;
    float s = 0.f;
#pragma unroll 16
    for (int kk = 0; kk < 256; ++kk)
      s += p[kk] * w[(size_t)kk * HDIM];
    red[ks][ln] = s;
    __syncthreads();
    if (ks == 0)
      protoC[j * HDIM + n] = red[0][ln] + red[1][ln] + red[2][ln] + red[3][ln] + b1[n];
  }
}

// ---------------------------------------------------------------------------
// 256x256 8-phase bf16 GEMM (K=1024), schedule v2 (m201-faithful). UNCHANGED
// from R4 (refcheck-proven, 87.5 us, MfmaUtil 31%).
// 512 threads = 8 waves as 2M x 4N; per-wave output 128x64; BK=64.
// LDS 128 KB: per operand [2 buf][2 ksub][2 half][128 rows][32 el], XOR
// piece-swizzle (slot p holds global piece p ^ ((row>>1)&3)) staged via
// pre-swizzled global source (rule 21).
//
// Per K-tile kt (buf p = kt&1), quadrants (a0,b0),(a0,b1),(a1,b1),(a1,b0):
//   ph0: dsr av<-A-lo(8), bvlo<-B-lo(4); stage T+1:A-hi->p^1; bar; MFMA q00; bar
//   ph1: dsr bvhi<-B-hi(4);              stage T+1:B-lo->p^1; bar; MFMA q01; bar
//   ph2: dsr av<-A-hi(8);                stage T+2:A-lo->p;   bar; MFMA q11; bar
//   ph3: (regs held)                     stage T+2:B-hi->p;   vmcnt(4); bar; MFMA q10; bar
// Reads of tile T happen only after tile T-1's ph3 barrier, which follows
// every wave's vmcnt(4) -> all waves' T loads landed (RAW safe globally).
// Restage of T+2 into the current buf is separated from that slice's last
// read by >=2 barriers (WAR safe). One vmcnt(4) per tile; never vmcnt(0).
// EPI=1: out = relu(acc + protoC[idx[row]][col]) -> bf16   (protoC holds b1)
// EPI=0: out = acc + bias[col] -> f32
// ---------------------------------------------------------------------------
template <int EPI>
__global__ __launch_bounds__(512, 2) void gemm256(
    const unsigned short* __restrict__ A,   // [M][1024] bf16
    const unsigned short* __restrict__ Bt,  // [1024][1024] bf16, n-major
    const int* __restrict__ idx,            // [M]            (EPI=1)
    const float* __restrict__ protoC,       // [NFAM][1024]   (EPI=1)
    const float* __restrict__ bias,         // [1024]         (EPI=0)
    unsigned short* __restrict__ outB,      // [M][1024] bf16 (EPI=1)
    float* __restrict__ outF) {             // [M][1024] f32  (EPI=0)
  constexpr int K  = 1024;
  constexpr int NT = K / 64;                   // 16 K-tiles
  __shared__ unsigned short ldsA[2 * 2 * 2 * 128 * 32];  // 64 KB
  __shared__ unsigned short ldsB[2 * 2 * 2 * 128 * 32];  // 64 KB

  const int t    = threadIdx.x;
  const int lane = t & 63;
  const int quad = lane >> 4;
  const int r16  = lane & 15;
  const int wid  = t >> 6;
  const int wm   = wid >> 2;                   // 0..1
  const int wn   = wid & 3;                    // 0..3

  // XCD-aware decode: xcd = b&7 owns row-panels [xcd*16, +16), sweeps 4 cols.
  const int b = blockIdx.x;
  const int rowBase = ((b >> 5) + (b & 7) * 16) * 256;
  const int colBase = ((b >> 3) & 3) * 256;

  // staging: thread t covers slice-row sr = t>>2, piece p = t&3 of each
  // 8 KB (ksub,half) slice; swizzled global piece q = p ^ ((sr>>1)&3).
  const int sr = t >> 2;
  const int q  = (t & 3) ^ ((t >> 3) & 3);
  const unsigned short* pA = A  + (size_t)(rowBase + sr) * K + q * 8;
  const unsigned short* pB = Bt + (size_t)(colBase + sr) * K + q * 8;
  const int ldst = t * 8;                      // thread's element offset in a slice

  // reader piece (per-lane constant)
  const int pr = quad ^ ((r16 >> 1) & 3);

  f32x4 acc[2][2][4][2];                       // [ah][bh][mi][ni]
#pragma unroll
  for (int a0 = 0; a0 < 2; ++a0)
#pragma unroll
    for (int b0 = 0; b0 < 2; ++b0)
#pragma unroll
      for (int m0 = 0; m0 < 4; ++m0)
#pragma unroll
        for (int n0 = 0; n0 < 2; ++n0) acc[a0][b0][m0][n0] = (f32x4){0.f, 0.f, 0.f, 0.f};

#define STAGE_A(buf, h, kb)                                                        \
  {                                                                                \
    async_cp16(ldsA + (buf) * 16384 + (0 * 2 + (h)) * 4096 + ldst,                 \
               pA + (size_t)(h) * (128 * K) + (kb) + 0 * 32);                      \
    async_cp16(ldsA + (buf) * 16384 + (1 * 2 + (h)) * 4096 + ldst,                 \
               pA + (size_t)(h) * (128 * K) + (kb) + 1 * 32);                      \
  }
#define STAGE_B(buf, h, kb)                                                        \
  {                                                                                \
    async_cp16(ldsB + (buf) * 16384 + (0 * 2 + (h)) * 4096 + ldst,                 \
               pB + (size_t)(h) * (128 * K) + (kb) + 0 * 32);                      \
    async_cp16(ldsB + (buf) * 16384 + (1 * 2 + (h)) * 4096 + ldst,                 \
               pB + (size_t)(h) * (128 * K) + (kb) + 1 * 32);                      \
  }
#define READ_A(dst, p_, h)                                                          \
  _Pragma("unroll")                                                                 \
  for (int s = 0; s < 2; ++s)                                                       \
    _Pragma("unroll")                                                               \
    for (int mi = 0; mi < 4; ++mi)                                                  \
      dst[s][mi] = *(const bf16x8*)(ldsA + (p_) * 16384 + (s * 2 + (h)) * 4096 +    \
                                    (wm * 64 + mi * 16 + r16) * 32 + pr * 8);
#define READ_B(dst, p_, h)                                                          \
  _Pragma("unroll")                                                                 \
  for (int s = 0; s < 2; ++s)                                                       \
    _Pragma("unroll")                                                               \
    for (int ni = 0; ni < 2; ++ni)                                                  \
      dst[s][ni] = *(const bf16x8*)(ldsB + (p_) * 16384 + (s * 2 + (h)) * 4096 +    \
                                    (wn * 32 + ni * 16 + r16) * 32 + pr * 8);
#define MFMA_Q(ah, bh, bsrc)                                                        \
  __builtin_amdgcn_s_setprio(1);                                                    \
  _Pragma("unroll")                                                                 \
  for (int s = 0; s < 2; ++s)                                                       \
    _Pragma("unroll")                                                               \
    for (int mi = 0; mi < 4; ++mi)                                                  \
      _Pragma("unroll")                                                             \
      for (int ni = 0; ni < 2; ++ni)                                                \
        acc[ah][bh][mi][ni] = __builtin_amdgcn_mfma_f32_16x16x32_bf16(              \
            av[s][mi], bsrc[s][ni], acc[ah][bh][mi][ni], 0, 0, 0);                  \
  __builtin_amdgcn_s_setprio(0);

  // prologue: issue order matches steady state (per tile: A-lo, B-hi, A-hi, B-lo)
  STAGE_A(0, 0, 0);        // T0 A-lo
  STAGE_B(0, 1, 0);        // T0 B-hi
  STAGE_A(0, 1, 0);        // T0 A-hi
  STAGE_B(0, 0, 0);        // T0 B-lo
  STAGE_A(1, 0, 64);       // T1 A-lo
  STAGE_B(1, 1, 64);       // T1 B-hi
  asm volatile("s_waitcnt vmcnt(4)" ::: "memory");   // T0 fully landed
  __builtin_amdgcn_s_barrier();

  bf16x8 av[2][4], bvlo[2][2], bvhi[2][2];

  for (int kt = 0; kt < NT; ++kt) {
    const int p   = kt & 1;
    const int kb1 = ((kt + 1) & (NT - 1)) * 64;
    const int kb2 = ((kt + 2) & (NT - 1)) * 64;

    // ph0: q(a0,b0)
    READ_A(av, p, 0);
    READ_B(bvlo, p, 0);
    STAGE_A(p ^ 1, 1, kb1);                 // T+1 A-hi
    __builtin_amdgcn_s_barrier();
    MFMA_Q(0, 0, bvlo);
    __builtin_amdgcn_s_barrier();

    // ph1: q(a0,b1)
    READ_B(bvhi, p, 1);
    STAGE_B(p ^ 1, 0, kb1);                 // T+1 B-lo
    __builtin_amdgcn_s_barrier();
    MFMA_Q(0, 1, bvhi);
    __builtin_amdgcn_s_barrier();

    // ph2: q(a1,b1)
    READ_A(av, p, 1);
    STAGE_A(p, 0, kb2);                     // T+2 A-lo (same buf; A-lo last read ph0)
    __builtin_amdgcn_s_barrier();
    MFMA_Q(1, 1, bvhi);
    __builtin_amdgcn_s_barrier();

    // ph3: q(a1,b0)  (all operands already in registers)
    STAGE_B(p, 1, kb2);                     // T+2 B-hi (same buf; B-hi last read ph1)
    asm volatile("s_waitcnt vmcnt(4)" ::: "memory");  // all of T+1 landed
    __builtin_amdgcn_s_barrier();
    MFMA_Q(1, 0, bvlo);
    __builtin_amdgcn_s_barrier();
  }
#undef STAGE_A
#undef STAGE_B
#undef READ_A
#undef READ_B
#undef MFMA_Q

  // epilogue: C/D layout col=lane&15, row=quad*4+reg  [m89/m91]
#pragma unroll
  for (int ah = 0; ah < 2; ++ah) {
#pragma unroll
    for (int mi = 0; mi < 4; ++mi) {
      const int grow0 = rowBase + ah * 128 + wm * 64 + mi * 16 + quad * 4;
      int pid[4];
      if (EPI) {
#pragma unroll
        for (int r = 0; r < 4; ++r) pid[r] = idx[grow0 + r];  // L2-hot
      }
#pragma unroll
      for (int bh = 0; bh < 2; ++bh) {
#pragma unroll
        for (int ni = 0; ni < 2; ++ni) {
          const int gcol = colBase + bh * 128 + wn * 32 + ni * 16 + r16;
          if (EPI) {
#pragma unroll
            for (int r = 0; r < 4; ++r) {
              float v = acc[ah][bh][mi][ni][r] + protoC[(size_t)pid[r] * HDIM + gcol];
              v = fmaxf(v, 0.0f);
              outB[(size_t)(grow0 + r) * 1024 + gcol] = f2bf(v);
            }
          } else {
            const float bv = bias[gcol];
#pragma unroll
            for (int r = 0; r < 4; ++r)
              outF[(size_t)(grow0 + r) * 1024 + gcol] = acc[ah][bh][mi][ni][r] + bv;
          }
        }
      }
    }
  }
}

// ---------------------------------------------------------------------------
// Workspace layout (~134 MB): featsB | hiddenB | W1t | W2t | protoC | idx
// ---------------------------------------------------------------------------
extern "C" void kernel_launch(void* const* d_in, const int* in_sizes, int n_in,
                              void* d_out, int out_size, void* d_ws, size_t ws_size,
                              hipStream_t stream) {
  const float* feats  = (const float*)d_in[0];
  const float* protos = (const float*)d_in[1];
  const float* W1     = (const float*)d_in[2];
  const float* b1     = (const float*)d_in[3];
  const float* W2     = (const float*)d_in[4];
  const float* b2     = (const float*)d_in[5];
  float* out = (float*)d_out;

  unsigned short* featsB  = (unsigned short*)d_ws;
  unsigned short* hiddenB = featsB + (size_t)BATCH * HDIM;
  unsigned short* W1t     = hiddenB + (size_t)BATCH * HDIM;   // top half only
  unsigned short* W2t     = W1t + (size_t)HDIM * HDIM;
  float* protoC = (float*)(W2t + (size_t)HDIM * HDIM);        // [NFAM][HDIM]
  int* idx      = (int*)(protoC + NFAM * HDIM);

  // one fused prep dispatch: nearest+cast+p2, both weight transposes, protoC
  prep_kernel<<<PREP_BLKS, 256, 0, stream>>>(
      feats, protos, W1, b1, W2, featsB, idx, protoC, W1t, W2t);
  // GEMM1: hidden = relu(feats @ W1top + protoC[idx])     K=1024
  gemm256<1><<<512, 512, 0, stream>>>(featsB, W1t, idx, protoC, nullptr, hiddenB, nullptr);
  // GEMM2: out = hidden @ W2 + b2                          K=1024
  gemm256<0><<<512, 512, 0, stream>>>(hiddenB, W2t, nullptr, nullptr, b2, nullptr, out);
}